// Round 4
// baseline (149.097 us; speedup 1.0000x reference)
//
#include <hip/hip_runtime.h>
#include <hip/hip_bf16.h>
#include <math.h>

#define EMBED  128
#define NUM_C  64
#define EPS    1e-5f
#define NPB    16            // nodes per block; 4 waves share them (16 centroids each)

typedef __attribute__((ext_vector_type(8))) short bf16x8;   // MFMA A/B frag (8 bf16)
typedef __attribute__((ext_vector_type(4))) float f32x4;    // MFMA C/D frag

__device__ __forceinline__ bf16x8 pack8(float4 x, float4 y) {
    __hip_bfloat162 p0 = __float22bfloat162_rn(float2{x.x, x.y});
    __hip_bfloat162 p1 = __float22bfloat162_rn(float2{x.z, x.w});
    __hip_bfloat162 p2 = __float22bfloat162_rn(float2{y.x, y.y});
    __hip_bfloat162 p3 = __float22bfloat162_rn(float2{y.z, y.w});
    union { __hip_bfloat162 h[4]; bf16x8 v; } u;
    u.h[0] = p0; u.h[1] = p1; u.h[2] = p2; u.h[3] = p3;
    return u.v;
}

// One block: 16 nodes x 64 centroids. Wave w owns centroid group [w*16, w*16+16).
// No LDS, no __syncthreads -- MFMA frags load straight from global (fp32->bf16).
__global__ __launch_bounds__(256) void cd_main(
    const float* __restrict__ node_repr,   // [N,128]
    const float* __restrict__ mask,        // [N,1]
    const float* __restrict__ cent,        // [64,128]
    float* __restrict__ out,               // [64 + N*64]
    float* __restrict__ colsum,            // [nb*64]  (or acc[64] in atomic mode)
    float* __restrict__ msum,              // [nb]     (or &acc[64])
    int N, int atomicMode)
{
    const int tid   = threadIdx.x;
    const int lane  = tid & 63;
    const int cw    = (tid >> 6) * 16;     // wave's centroid base
    const int node0 = blockIdx.x * NPB;
    const int quad  = lane >> 4;           // 0..3 (k-slice for A/B frags)
    const int lm    = lane & 15;           // A: node row; B: centroid col; D: col

    const int arow  = node0 + lm;
    const int arowc = arow < N ? arow : N - 1;          // clamp for tail safety
    const float* ap = node_repr + (long)arowc * EMBED + quad * 8;
    const float* bp = cent + (long)(cw + lm) * EMBED + quad * 8;

    float sup = 0.f, svp = 0.f;
    f32x4 acc = {0.f, 0.f, 0.f, 0.f};

    // K-loop: 4 steps of K=32. A-frag: A[m=lm][k=quad*8+j]; B-frag: B[k][n=lm].
    #pragma unroll
    for (int ks = 0; ks < 4; ++ks) {
        float4 a0 = *(const float4*)(ap + ks * 32);
        float4 a1 = *(const float4*)(ap + ks * 32 + 4);
        float4 b0 = *(const float4*)(bp + ks * 32);
        float4 b1 = *(const float4*)(bp + ks * 32 + 4);
        // fp32 partial norms from the same loaded values (exact inputs)
        sup = fmaf(a0.x,a0.x, fmaf(a0.y,a0.y, fmaf(a0.z,a0.z, fmaf(a0.w,a0.w, sup))));
        sup = fmaf(a1.x,a1.x, fmaf(a1.y,a1.y, fmaf(a1.z,a1.z, fmaf(a1.w,a1.w, sup))));
        svp = fmaf(b0.x,b0.x, fmaf(b0.y,b0.y, fmaf(b0.z,b0.z, fmaf(b0.w,b0.w, svp))));
        svp = fmaf(b1.x,b1.x, fmaf(b1.y,b1.y, fmaf(b1.z,b1.z, fmaf(b1.w,b1.w, svp))));
        acc = __builtin_amdgcn_mfma_f32_16x16x32_bf16(pack8(a0, a1), pack8(b0, b1), acc, 0, 0, 0);
    }

    // Each lane holds a k-slice partial; lanes {m, m+16, m+32, m+48} complete row m.
    sup += __shfl_xor(sup, 16); sup += __shfl_xor(sup, 32);   // su for node0+lm, all lanes
    svp += __shfl_xor(svp, 16); svp += __shfl_xor(svp, 32);   // sv for cent cw+lm, all lanes

    const float mk_l = mask[arowc];
    const float mkv  = (arow < N) ? mk_l : 0.f;

    // Epilogue. D layout: col = lm (centroid), row = quad*4 + r (node).
    float gacc = 0.f;
    #pragma unroll
    for (int r = 0; r < 4; ++r) {
        const int m = quad * 4 + r;
        const int n = node0 + m;
        const float su_m = __shfl(sup, m);     // su lives on lane index lm==m
        const float mk_m = __shfl(mkv, m);
        float sq    = fmaxf(su_m + svp - 2.f * acc[r], 0.f);
        float denom = fmaxf((1.f - su_m) * (1.f - svp), EPS);
        float t     = fmaxf(2.f * sq / denom, EPS);
        float dist  = log1pf(t + sqrtf(t * (t + 2.f)));   // arccosh(1+t), stable
        float v     = dist * mk_m;
        if (n < N) {
            out[NUM_C + (long)n * NUM_C + cw + lm] = v;   // 16-lane rows, full 64B lines
            gacc += v;
        }
    }

    // Column sums over this block's 16 nodes (per wave: 16 centroids)
    gacc += __shfl_xor(gacc, 16); gacc += __shfl_xor(gacc, 32);
    if (quad == 0) {
        if (atomicMode) atomicAdd(&colsum[cw + lm], gacc);
        else            colsum[(long)blockIdx.x * NUM_C + cw + lm] = gacc;
    }

    // Block mask sum (wave 0): mkv is replicated 4x across quads -> sum all, /4
    if (tid < 64) {
        float ms = mkv;
        #pragma unroll
        for (int k = 32; k; k >>= 1) ms += __shfl_xor(ms, k, 64);
        ms *= 0.25f;
        if (lane == 0) {
            if (atomicMode) atomicAdd(&msum[0], ms);
            else            msum[blockIdx.x] = ms;
        }
    }
}

// Reduce per-block partials -> out[0..63]
__global__ __launch_bounds__(256) void cd_fin(
    const float* __restrict__ colsum, const float* __restrict__ msum,
    float* __restrict__ out, int nb)
{
    __shared__ float red[256];
    __shared__ float mtot_s;
    const int tid = threadIdx.x;

    float m = 0.f;
    for (int b = tid; b < nb; b += 256) m += msum[b];
    #pragma unroll
    for (int k = 32; k; k >>= 1) m += __shfl_xor(m, k, 64);
    if ((tid & 63) == 0) red[tid >> 6] = m;
    __syncthreads();
    if (tid == 0) mtot_s = red[0] + red[1] + red[2] + red[3];
    __syncthreads();

    const int c = tid & 63, q = tid >> 6;
    float s = 0.f;
    for (int b = q; b < nb; b += 4) s += colsum[(long)b * NUM_C + c];
    red[tid] = s;
    __syncthreads();
    if (q == 0)
        out[c] = (red[c] + red[64 + c] + red[128 + c] + red[192 + c]) / mtot_s;
}

// atomic-mode fallback helpers
__global__ void cd_zero(float* acc) { if (threadIdx.x < NUM_C + 1) acc[threadIdx.x] = 0.f; }
__global__ void cd_fin_atomic(const float* __restrict__ acc, float* __restrict__ out) {
    int c = threadIdx.x;
    if (c < NUM_C) out[c] = acc[c] / acc[NUM_C];
}

extern "C" void kernel_launch(void* const* d_in, const int* in_sizes, int n_in,
                              void* d_out, int out_size, void* d_ws, size_t ws_size,
                              hipStream_t stream) {
    const float* node_repr = (const float*)d_in[0];
    const float* mask      = (const float*)d_in[1];
    const float* cent      = (const float*)d_in[2];
    float* out = (float*)d_out;

    const int N  = in_sizes[0] / EMBED;
    const int nb = (N + NPB - 1) / NPB;
    const size_t needed = (size_t)nb * NUM_C * sizeof(float) + (size_t)nb * sizeof(float);

    if (ws_size >= needed) {
        float* colsum = (float*)d_ws;
        float* msum   = colsum + (size_t)nb * NUM_C;
        cd_main<<<nb, 256, 0, stream>>>(node_repr, mask, cent, out, colsum, msum, N, 0);
        cd_fin<<<1, 256, 0, stream>>>(colsum, msum, out, nb);
    } else {
        float* acc = (float*)d_ws;   // 65 floats
        cd_zero<<<1, 128, 0, stream>>>(acc);
        cd_main<<<nb, 256, 0, stream>>>(node_repr, mask, cent, out, acc, acc + NUM_C, N, 1);
        cd_fin_atomic<<<1, 64, 0, stream>>>(acc, out);
    }
}

// Round 5
// 83.142 us; speedup vs baseline: 1.7933x; 1.7933x over previous
//
#include <hip/hip_runtime.h>
#include <hip/hip_bf16.h>
#include <math.h>

#define EMBED  128
#define NUM_C  64
#define EPS    1e-5f
#define NPB    16            // nodes per block; 4 waves share them (16 centroids each)
#define NPART  64            // stage-1 reduce blocks

typedef __attribute__((ext_vector_type(8))) short bf16x8;   // MFMA A/B frag (8 bf16)
typedef __attribute__((ext_vector_type(4))) float f32x4;    // MFMA C/D frag

__device__ __forceinline__ bf16x8 pack8(float4 x, float4 y) {
    __hip_bfloat162 p0 = __float22bfloat162_rn(float2{x.x, x.y});
    __hip_bfloat162 p1 = __float22bfloat162_rn(float2{x.z, x.w});
    __hip_bfloat162 p2 = __float22bfloat162_rn(float2{y.x, y.y});
    __hip_bfloat162 p3 = __float22bfloat162_rn(float2{y.z, y.w});
    union { __hip_bfloat162 h[4]; bf16x8 v; } u;
    u.h[0] = p0; u.h[1] = p1; u.h[2] = p2; u.h[3] = p3;
    return u.v;
}

// One block: 16 nodes x 64 centroids. Wave w owns centroid group [w*16, w*16+16).
// No LDS, no __syncthreads -- MFMA frags load straight from global (fp32->bf16).
__global__ __launch_bounds__(256) void cd_main(
    const float* __restrict__ node_repr,   // [N,128]
    const float* __restrict__ mask,        // [N,1]
    const float* __restrict__ cent,        // [64,128]
    float* __restrict__ out,               // [64 + N*64]
    float* __restrict__ colsum,            // [nb*64]  (or acc[64] in atomic mode)
    float* __restrict__ msum,              // [nb]     (or &acc[64])
    int N, int atomicMode)
{
    const int tid   = threadIdx.x;
    const int lane  = tid & 63;
    const int cw    = (tid >> 6) * 16;     // wave's centroid base
    const int node0 = blockIdx.x * NPB;
    const int quad  = lane >> 4;           // 0..3 (k-slice for A/B frags)
    const int lm    = lane & 15;           // A: node row; B: centroid col; D: col

    const int arow  = node0 + lm;
    const int arowc = arow < N ? arow : N - 1;          // clamp for tail safety
    const float* ap = node_repr + (long)arowc * EMBED + quad * 8;
    const float* bp = cent + (long)(cw + lm) * EMBED + quad * 8;

    float sup = 0.f, svp = 0.f;
    f32x4 acc = {0.f, 0.f, 0.f, 0.f};

    // K-loop: 4 steps of K=32. A-frag: A[m=lm][k=quad*8+j]; B-frag: B[k][n=lm].
    #pragma unroll
    for (int ks = 0; ks < 4; ++ks) {
        float4 a0 = *(const float4*)(ap + ks * 32);
        float4 a1 = *(const float4*)(ap + ks * 32 + 4);
        float4 b0 = *(const float4*)(bp + ks * 32);
        float4 b1 = *(const float4*)(bp + ks * 32 + 4);
        // fp32 partial norms from the same loaded values (exact inputs)
        sup = fmaf(a0.x,a0.x, fmaf(a0.y,a0.y, fmaf(a0.z,a0.z, fmaf(a0.w,a0.w, sup))));
        sup = fmaf(a1.x,a1.x, fmaf(a1.y,a1.y, fmaf(a1.z,a1.z, fmaf(a1.w,a1.w, sup))));
        svp = fmaf(b0.x,b0.x, fmaf(b0.y,b0.y, fmaf(b0.z,b0.z, fmaf(b0.w,b0.w, svp))));
        svp = fmaf(b1.x,b1.x, fmaf(b1.y,b1.y, fmaf(b1.z,b1.z, fmaf(b1.w,b1.w, svp))));
        acc = __builtin_amdgcn_mfma_f32_16x16x32_bf16(pack8(a0, a1), pack8(b0, b1), acc, 0, 0, 0);
    }

    // Each lane holds a k-slice partial; lanes {m, m+16, m+32, m+48} complete row m.
    sup += __shfl_xor(sup, 16); sup += __shfl_xor(sup, 32);   // su for node0+lm, all lanes
    svp += __shfl_xor(svp, 16); svp += __shfl_xor(svp, 32);   // sv for cent cw+lm, all lanes

    const float mk_l = mask[arowc];
    const float mkv  = (arow < N) ? mk_l : 0.f;

    // Epilogue. D layout: col = lm (centroid), row = quad*4 + r (node).
    float gacc = 0.f;
    #pragma unroll
    for (int r = 0; r < 4; ++r) {
        const int m = quad * 4 + r;
        const int n = node0 + m;
        const float su_m = __shfl(sup, m);     // su lives on lane index lm==m
        const float mk_m = __shfl(mkv, m);
        float sq    = fmaxf(su_m + svp - 2.f * acc[r], 0.f);
        float denom = fmaxf((1.f - su_m) * (1.f - svp), EPS);
        float t     = fmaxf(2.f * sq / denom, EPS);
        float dist  = log1pf(t + sqrtf(t * (t + 2.f)));   // arccosh(1+t), stable
        float v     = dist * mk_m;
        if (n < N) {
            out[NUM_C + (long)n * NUM_C + cw + lm] = v;   // 16-lane rows, full 64B lines
            gacc += v;
        }
    }

    // Column sums over this block's 16 nodes (per wave: 16 centroids)
    gacc += __shfl_xor(gacc, 16); gacc += __shfl_xor(gacc, 32);
    if (quad == 0) {
        if (atomicMode) atomicAdd(&colsum[cw + lm], gacc);
        else            colsum[(long)blockIdx.x * NUM_C + cw + lm] = gacc;
    }

    // Block mask sum (wave 0): mkv is replicated 4x across quads -> sum all, /4
    if (tid < 64) {
        float ms = mkv;
        #pragma unroll
        for (int k = 32; k; k >>= 1) ms += __shfl_xor(ms, k, 64);
        ms *= 0.25f;
        if (lane == 0) {
            if (atomicMode) atomicAdd(&msum[0], ms);
            else            msum[blockIdx.x] = ms;
        }
    }
}

// Stage-1 reduce: NPART blocks, block g sums its chunk of colsum rows + msum.
__global__ __launch_bounds__(256) void cd_part(
    const float* __restrict__ colsum, const float* __restrict__ msum,
    float* __restrict__ colsum2, float* __restrict__ msum2, int nb)
{
    __shared__ float red[256];
    __shared__ float mred[4];
    const int g     = blockIdx.x;
    const int tid   = threadIdx.x;
    const int c     = tid & 63, q = tid >> 6;
    const int chunk = (nb + NPART - 1) / NPART;
    const int b0    = g * chunk;
    const int b1    = (b0 + chunk < nb) ? b0 + chunk : nb;

    float s = 0.f;
    #pragma unroll 4
    for (int b = b0 + q; b < b1; b += 4) s += colsum[(long)b * NUM_C + c];
    red[tid] = s;

    float m = 0.f;
    for (int b = b0 + tid; b < b1; b += 256) m += msum[b];
    #pragma unroll
    for (int k = 32; k; k >>= 1) m += __shfl_xor(m, k, 64);
    if ((tid & 63) == 0) mred[tid >> 6] = m;
    __syncthreads();

    if (q == 0) colsum2[(long)g * NUM_C + c] = red[c] + red[64 + c] + red[128 + c] + red[192 + c];
    if (tid == 0) msum2[g] = mred[0] + mred[1] + mred[2] + mred[3];
}

// Stage-2: one block reduces NPART partial rows and divides.
__global__ __launch_bounds__(256) void cd_fin2(
    const float* __restrict__ colsum2, const float* __restrict__ msum2,
    float* __restrict__ out)
{
    __shared__ float red[256];
    __shared__ float mt;
    const int tid = threadIdx.x;
    const int c = tid & 63, q = tid >> 6;

    float m = (tid < NPART) ? msum2[tid] : 0.f;     // NPART==64: wave 0 covers it
    #pragma unroll
    for (int k = 32; k; k >>= 1) m += __shfl_xor(m, k, 64);
    if (tid == 0) mt = m;

    float s = 0.f;
    #pragma unroll
    for (int b = q; b < NPART; b += 4) s += colsum2[b * NUM_C + c];
    red[tid] = s;
    __syncthreads();
    if (q == 0) out[c] = (red[c] + red[64 + c] + red[128 + c] + red[192 + c]) / mt;
}

// atomic-mode fallback helpers
__global__ void cd_zero(float* acc) { if (threadIdx.x < NUM_C + 1) acc[threadIdx.x] = 0.f; }
__global__ void cd_fin_atomic(const float* __restrict__ acc, float* __restrict__ out) {
    int c = threadIdx.x;
    if (c < NUM_C) out[c] = acc[c] / acc[NUM_C];
}

extern "C" void kernel_launch(void* const* d_in, const int* in_sizes, int n_in,
                              void* d_out, int out_size, void* d_ws, size_t ws_size,
                              hipStream_t stream) {
    const float* node_repr = (const float*)d_in[0];
    const float* mask      = (const float*)d_in[1];
    const float* cent      = (const float*)d_in[2];
    float* out = (float*)d_out;

    const int N  = in_sizes[0] / EMBED;
    const int nb = (N + NPB - 1) / NPB;
    const size_t needed = ((size_t)nb * NUM_C + nb + NPART * NUM_C + NPART) * sizeof(float);

    if (ws_size >= needed) {
        float* colsum  = (float*)d_ws;
        float* msum    = colsum + (size_t)nb * NUM_C;
        float* colsum2 = msum + nb;
        float* msum2   = colsum2 + NPART * NUM_C;
        cd_main<<<nb, 256, 0, stream>>>(node_repr, mask, cent, out, colsum, msum, N, 0);
        cd_part<<<NPART, 256, 0, stream>>>(colsum, msum, colsum2, msum2, nb);
        cd_fin2<<<1, 256, 0, stream>>>(colsum2, msum2, out);
    } else {
        float* acc = (float*)d_ws;   // 65 floats
        cd_zero<<<1, 128, 0, stream>>>(acc);
        cd_main<<<nb, 256, 0, stream>>>(node_repr, mask, cent, out, acc, acc + NUM_C, N, 1);
        cd_fin_atomic<<<1, 64, 0, stream>>>(acc, out);
    }
}

// Round 6
// 75.835 us; speedup vs baseline: 1.9661x; 1.0964x over previous
//
#include <hip/hip_runtime.h>
#include <hip/hip_bf16.h>
#include <math.h>

#define EMBED  128
#define NUM_C  64
#define EPS    1e-5f
#define NPB    32            // nodes per block (two 16-row MFMA tiles, B-frag reused)

typedef __attribute__((ext_vector_type(8))) short bf16x8;   // MFMA A/B frag (8 bf16)
typedef __attribute__((ext_vector_type(4))) float f32x4;    // MFMA C/D frag

__device__ __forceinline__ bf16x8 pack8(float4 x, float4 y) {
    __hip_bfloat162 p0 = __float22bfloat162_rn(float2{x.x, x.y});
    __hip_bfloat162 p1 = __float22bfloat162_rn(float2{x.z, x.w});
    __hip_bfloat162 p2 = __float22bfloat162_rn(float2{y.x, y.y});
    __hip_bfloat162 p3 = __float22bfloat162_rn(float2{y.z, y.w});
    union { __hip_bfloat162 h[4]; bf16x8 v; } u;
    u.h[0] = p0; u.h[1] = p1; u.h[2] = p2; u.h[3] = p3;
    return u.v;
}

// One block: 32 nodes x 64 centroids. Wave w owns centroid group [w*16, w*16+16)
// and computes BOTH 16-node tiles with one packed B fragment (2 MFMAs/k-step).
// No LDS in the main path, no __syncthreads.
__global__ __launch_bounds__(256) void cd_main(
    const float* __restrict__ node_repr,   // [N,128]
    const float* __restrict__ mask,        // [N,1]
    const float* __restrict__ cent,        // [64,128]
    float* __restrict__ out,               // [64 + N*64]
    float* __restrict__ colsum,            // [nb*64]  (or acc[64] in atomic mode)
    float* __restrict__ msum,              // [nb]     (or &acc[64])
    int N, int atomicMode)
{
    const int tid   = threadIdx.x;
    const int lane  = tid & 63;
    const int cw    = (tid >> 6) * 16;     // wave's centroid base
    const int node0 = blockIdx.x * NPB;
    const int quad  = lane >> 4;           // 0..3 (k-slice for A/B frags)
    const int lm    = lane & 15;           // A: node row; B: centroid col; D: col

    const int arow0  = node0 + lm;
    const int arow1  = node0 + 16 + lm;
    const int arow0c = arow0 < N ? arow0 : N - 1;   // clamp for tail safety
    const int arow1c = arow1 < N ? arow1 : N - 1;
    const float* ap0 = node_repr + (long)arow0c * EMBED + quad * 8;
    const float* ap1 = node_repr + (long)arow1c * EMBED + quad * 8;
    const float* bp  = cent + (long)(cw + lm) * EMBED + quad * 8;

    float sup0 = 0.f, sup1 = 0.f, svp = 0.f;
    f32x4 acc0 = {0.f, 0.f, 0.f, 0.f};
    f32x4 acc1 = {0.f, 0.f, 0.f, 0.f};

    // K-loop: 4 steps of K=32. One B pack feeds two MFMAs (node tiles 0/1).
    #pragma unroll
    for (int ks = 0; ks < 4; ++ks) {
        float4 a00 = *(const float4*)(ap0 + ks * 32);
        float4 a01 = *(const float4*)(ap0 + ks * 32 + 4);
        float4 a10 = *(const float4*)(ap1 + ks * 32);
        float4 a11 = *(const float4*)(ap1 + ks * 32 + 4);
        float4 b0  = *(const float4*)(bp  + ks * 32);
        float4 b1  = *(const float4*)(bp  + ks * 32 + 4);
        // fp32 partial norms from the same loaded values (exact inputs)
        sup0 = fmaf(a00.x,a00.x, fmaf(a00.y,a00.y, fmaf(a00.z,a00.z, fmaf(a00.w,a00.w, sup0))));
        sup0 = fmaf(a01.x,a01.x, fmaf(a01.y,a01.y, fmaf(a01.z,a01.z, fmaf(a01.w,a01.w, sup0))));
        sup1 = fmaf(a10.x,a10.x, fmaf(a10.y,a10.y, fmaf(a10.z,a10.z, fmaf(a10.w,a10.w, sup1))));
        sup1 = fmaf(a11.x,a11.x, fmaf(a11.y,a11.y, fmaf(a11.z,a11.z, fmaf(a11.w,a11.w, sup1))));
        svp  = fmaf(b0.x,b0.x, fmaf(b0.y,b0.y, fmaf(b0.z,b0.z, fmaf(b0.w,b0.w, svp))));
        svp  = fmaf(b1.x,b1.x, fmaf(b1.y,b1.y, fmaf(b1.z,b1.z, fmaf(b1.w,b1.w, svp))));
        bf16x8 bb = pack8(b0, b1);
        acc0 = __builtin_amdgcn_mfma_f32_16x16x32_bf16(pack8(a00, a01), bb, acc0, 0, 0, 0);
        acc1 = __builtin_amdgcn_mfma_f32_16x16x32_bf16(pack8(a10, a11), bb, acc1, 0, 0, 0);
    }

    // Lane holds a k-slice partial; lanes {m, m+16, m+32, m+48} complete row m.
    sup0 += __shfl_xor(sup0, 16); sup0 += __shfl_xor(sup0, 32);
    sup1 += __shfl_xor(sup1, 16); sup1 += __shfl_xor(sup1, 32);
    svp  += __shfl_xor(svp, 16);  svp  += __shfl_xor(svp, 32);

    const float mkv0 = (arow0 < N) ? mask[arow0c] : 0.f;
    const float mkv1 = (arow1 < N) ? mask[arow1c] : 0.f;

    // Epilogue. D layout: col = lm (centroid), row = quad*4 + r (node).
    const float sv1 = 1.f - svp;
    float gacc = 0.f;
    #pragma unroll
    for (int r = 0; r < 4; ++r) {
        const int m = quad * 4 + r;
        // tile 0
        {
            const int n = node0 + m;
            const float su_m = __shfl(sup0, m);
            const float mk_m = __shfl(mkv0, m);
            float sq    = fmaxf(su_m + svp - 2.f * acc0[r], 0.f);
            float denom = fmaxf((1.f - su_m) * sv1, EPS);
            float t     = fmaxf(2.f * sq / denom, EPS);
            float dist  = __logf(1.f + t + sqrtf(t * (t + 2.f)));  // arccosh(1+t)
            float v     = dist * mk_m;
            if (n < N) {
                out[NUM_C + (long)n * NUM_C + cw + lm] = v;
                gacc += v;
            }
        }
        // tile 1
        {
            const int n = node0 + 16 + m;
            const float su_m = __shfl(sup1, m);
            const float mk_m = __shfl(mkv1, m);
            float sq    = fmaxf(su_m + svp - 2.f * acc1[r], 0.f);
            float denom = fmaxf((1.f - su_m) * sv1, EPS);
            float t     = fmaxf(2.f * sq / denom, EPS);
            float dist  = __logf(1.f + t + sqrtf(t * (t + 2.f)));
            float v     = dist * mk_m;
            if (n < N) {
                out[NUM_C + (long)n * NUM_C + cw + lm] = v;
                gacc += v;
            }
        }
    }

    // Column sums over this block's 32 nodes (per wave: its 16 centroids)
    gacc += __shfl_xor(gacc, 16); gacc += __shfl_xor(gacc, 32);
    if (quad == 0) {
        if (atomicMode) atomicAdd(&colsum[cw + lm], gacc);
        else            colsum[(long)blockIdx.x * NUM_C + cw + lm] = gacc;
    }

    // Block mask sum (wave 0): each node's mask appears in 4 lanes -> /4
    if (tid < 64) {
        float ms = mkv0 + mkv1;
        #pragma unroll
        for (int k = 32; k; k >>= 1) ms += __shfl_xor(ms, k, 64);
        ms *= 0.25f;
        if (lane == 0) {
            if (atomicMode) atomicAdd(&msum[0], ms);
            else            msum[blockIdx.x] = ms;
        }
    }
}

// Single-stage reduce: 64 blocks, block c sums column c + (redundantly) the mask.
__global__ __launch_bounds__(256) void cd_fin1(
    const float* __restrict__ colsum, const float* __restrict__ msum,
    float* __restrict__ out, int nb)
{
    __shared__ float rs[4], rm[4];
    const int c   = blockIdx.x;
    const int tid = threadIdx.x;

    float s = 0.f, m = 0.f;
    for (int b = tid; b < nb; b += 256) {
        s += colsum[(long)b * NUM_C + c];
        m += msum[b];
    }
    #pragma unroll
    for (int k = 32; k; k >>= 1) { s += __shfl_xor(s, k, 64); m += __shfl_xor(m, k, 64); }
    if ((tid & 63) == 0) { rs[tid >> 6] = s; rm[tid >> 6] = m; }
    __syncthreads();
    if (tid == 0)
        out[c] = (rs[0] + rs[1] + rs[2] + rs[3]) / (rm[0] + rm[1] + rm[2] + rm[3]);
}

// atomic-mode fallback helpers
__global__ void cd_zero(float* acc) { if (threadIdx.x < NUM_C + 1) acc[threadIdx.x] = 0.f; }
__global__ void cd_fin_atomic(const float* __restrict__ acc, float* __restrict__ out) {
    int c = threadIdx.x;
    if (c < NUM_C) out[c] = acc[c] / acc[NUM_C];
}

extern "C" void kernel_launch(void* const* d_in, const int* in_sizes, int n_in,
                              void* d_out, int out_size, void* d_ws, size_t ws_size,
                              hipStream_t stream) {
    const float* node_repr = (const float*)d_in[0];
    const float* mask      = (const float*)d_in[1];
    const float* cent      = (const float*)d_in[2];
    float* out = (float*)d_out;

    const int N  = in_sizes[0] / EMBED;
    const int nb = (N + NPB - 1) / NPB;
    const size_t needed = ((size_t)nb * NUM_C + nb) * sizeof(float);

    if (ws_size >= needed) {
        float* colsum = (float*)d_ws;
        float* msum   = colsum + (size_t)nb * NUM_C;
        cd_main<<<nb, 256, 0, stream>>>(node_repr, mask, cent, out, colsum, msum, N, 0);
        cd_fin1<<<NUM_C, 256, 0, stream>>>(colsum, msum, out, nb);
    } else {
        float* acc = (float*)d_ws;   // 65 floats
        cd_zero<<<1, 128, 0, stream>>>(acc);
        cd_main<<<nb, 256, 0, stream>>>(node_repr, mask, cent, out, acc, acc + NUM_C, N, 1);
        cd_fin_atomic<<<1, 64, 0, stream>>>(acc, out);
    }
}